// Round 2
// baseline (1167.821 us; speedup 1.0000x reference)
//
#include <hip/hip_runtime.h>
#include <hip/hip_fp16.h>

constexpr int NN = 50000;
constexpr int EE = 1600000;
constexpr int NB = 196;           // scan blocks: ceil(50000/256)

typedef __attribute__((ext_vector_type(8))) short bf16x8;
typedef __attribute__((ext_vector_type(4))) float f32x4;

__device__ inline short f2bf(float f) {
    unsigned u = __builtin_bit_cast(unsigned, f);
    u += 0x7fff + ((u >> 16) & 1);      // RNE to bf16
    return (short)(u >> 16);
}

// ---------------------------------------------------------------------------
// K1: node GEMMs. C[M,128] = x[M,128] @ W[128,128] + b, blockIdx.y selects
// {Wq,Wk,Wv,Wskip}. q/k/v -> fp16 head-interleaved tables, skip -> fp32 plain.
// Block = 256 thr (4 waves), block tile 64 rows x 128 cols, MFMA 16x16x32 bf16.
// LDS tiles XOR-swizzled in 16B chunks to keep frag reads 2-way-conflict free.
// ---------------------------------------------------------------------------
__global__ __launch_bounds__(256) void node_gemm(
    const float* __restrict__ x,
    const float* __restrict__ Wq, const float* __restrict__ bq,
    const float* __restrict__ Wk, const float* __restrict__ bk,
    const float* __restrict__ Wv, const float* __restrict__ bv,
    const float* __restrict__ Ws, const float* __restrict__ bs,
    __half* __restrict__ qt, __half* __restrict__ kt, __half* __restrict__ vt,
    float* __restrict__ skip)
{
    __shared__ short As[64 * 128];    // [row][chunk^(row&15)][8], 16 KB
    __shared__ short Bs[128 * 128];   // Wt: [n][chunk^(n&15)][8], 32 KB
    const int tid = threadIdx.x;
    const int mat = blockIdx.y;
    const float* __restrict__ W    = mat == 0 ? Wq : mat == 1 ? Wk : mat == 2 ? Wv : Ws;
    const float* __restrict__ bias = mat == 0 ? bq : mat == 1 ? bk : mat == 2 ? bv : bs;

    // stage W^T (bf16, swizzled): W is [k][n] row-major
    #pragma unroll 4
    for (int idx = tid; idx < 16384; idx += 256) {
        int k = idx >> 7, n = idx & 127;
        int chunk = (k >> 3) ^ (n & 15);
        Bs[n * 128 + chunk * 8 + (k & 7)] = f2bf(W[idx]);
    }
    // stage A tile
    const int row0 = blockIdx.x * 64;
    #pragma unroll 4
    for (int idx = tid; idx < 8192; idx += 256) {
        int r = idx >> 7, k = idx & 127;
        int node = row0 + r;
        float v = (node < NN) ? x[(size_t)node * 128 + k] : 0.f;
        int chunk = (k >> 3) ^ (r & 15);
        As[r * 128 + chunk * 8 + (k & 7)] = f2bf(v);
    }
    __syncthreads();

    const int wave = tid >> 6, lane = tid & 63;
    const int m16 = lane & 15, quad = lane >> 4;
    const int arow = wave * 16 + m16;
    f32x4 acc[8] = {};
    #pragma unroll
    for (int ks = 0; ks < 4; ks++) {
        int c = ks * 4 + quad;
        bf16x8 af = *(const bf16x8*)&As[arow * 128 + (c ^ (arow & 15)) * 8];
        #pragma unroll
        for (int t = 0; t < 8; t++) {
            int n = t * 16 + m16;
            bf16x8 bf = *(const bf16x8*)&Bs[n * 128 + (c ^ (n & 15)) * 8];
            acc[t] = __builtin_amdgcn_mfma_f32_16x16x32_bf16(af, bf, acc[t], 0, 0, 0);
        }
    }
    __half* __restrict__ T = mat == 0 ? qt : mat == 1 ? kt : vt;
    #pragma unroll
    for (int t = 0; t < 8; t++) {
        int col = t * 16 + m16;
        float bv_ = bias[col];
        #pragma unroll
        for (int r = 0; r < 4; r++) {
            int node = row0 + wave * 16 + quad * 4 + r;
            if (node < NN) {
                float val = acc[t][r] + bv_;
                if (mat < 3)
                    T[node * 128 + (col & 63) * 2 + (col >> 6)] = __float2half(val);
                else
                    skip[node * 128 + col] = val;
            }
        }
    }
}

// ---------------------------------------------------------------------------
// K2: e = edge_attr[E,64] @ We[64,128] -> fp16 head-interleaved et[E][64][2]
// ---------------------------------------------------------------------------
__global__ __launch_bounds__(256) void edge_gemm(
    const float* __restrict__ ea, const float* __restrict__ We,
    __half* __restrict__ et)
{
    __shared__ short As[64 * 64];     // [row][chunk^(row&7)][8], 8 KB
    __shared__ short Bs[128 * 64];    // We^T: [n][chunk^(n&7)][8], 16 KB
    const int tid = threadIdx.x;
    #pragma unroll 4
    for (int idx = tid; idx < 8192; idx += 256) {    // We is [k:64][n:128]
        int k = idx >> 7, n = idx & 127;
        int chunk = (k >> 3) ^ (n & 7);
        Bs[n * 64 + chunk * 8 + (k & 7)] = f2bf(We[idx]);
    }
    const int row0 = blockIdx.x * 64;
    #pragma unroll 4
    for (int idx = tid; idx < 4096; idx += 256) {
        int r = idx >> 6, k = idx & 63;
        int chunk = (k >> 3) ^ (r & 7);
        As[r * 64 + chunk * 8 + (k & 7)] = f2bf(ea[(size_t)(row0 + r) * 64 + k]);
    }
    __syncthreads();

    const int wave = tid >> 6, lane = tid & 63;
    const int m16 = lane & 15, quad = lane >> 4;
    const int arow = wave * 16 + m16;
    f32x4 acc[8] = {};
    #pragma unroll
    for (int ks = 0; ks < 2; ks++) {
        int c = ks * 4 + quad;
        bf16x8 af = *(const bf16x8*)&As[arow * 64 + (c ^ (arow & 7)) * 8];
        #pragma unroll
        for (int t = 0; t < 8; t++) {
            int n = t * 16 + m16;
            bf16x8 bf = *(const bf16x8*)&Bs[n * 64 + (c ^ (n & 7)) * 8];
            acc[t] = __builtin_amdgcn_mfma_f32_16x16x32_bf16(af, bf, acc[t], 0, 0, 0);
        }
    }
    #pragma unroll
    for (int t = 0; t < 8; t++) {
        int col = t * 16 + m16;
        int coff = (col & 63) * 2 + (col >> 6);
        #pragma unroll
        for (int r = 0; r < 4; r++) {
            int edge = row0 + wave * 16 + quad * 4 + r;
            et[(size_t)edge * 128 + coff] = __float2half(acc[t][r]);
        }
    }
}

// ---------------------------------------------------------------------------
// Counting sort of edges by dst: hist -> scan(3 kernels) -> scatter
// ---------------------------------------------------------------------------
__global__ void k_hist(const int* __restrict__ dst, int* __restrict__ cnt) {
    int i = blockIdx.x * 256 + threadIdx.x;
    if (i < EE) atomicAdd(&cnt[dst[i]], 1);
}

__global__ __launch_bounds__(256) void k_scan1(const int* __restrict__ cnt,
                                               int* __restrict__ offs,
                                               int* __restrict__ bsum) {
    __shared__ int s[256];
    int t = threadIdx.x, i = blockIdx.x * 256 + t;
    int v = (i < NN) ? cnt[i] : 0;
    s[t] = v; __syncthreads();
    #pragma unroll
    for (int d = 1; d < 256; d <<= 1) {
        int u = (t >= d) ? s[t - d] : 0;
        __syncthreads(); s[t] += u; __syncthreads();
    }
    if (i < NN) offs[i] = s[t] - v;
    if (t == 255) bsum[blockIdx.x] = s[255];
}

__global__ __launch_bounds__(256) void k_scan2(int* __restrict__ bsum) {
    __shared__ int s[256];
    int t = threadIdx.x;
    int v = (t < NB) ? bsum[t] : 0;
    s[t] = v; __syncthreads();
    #pragma unroll
    for (int d = 1; d < 256; d <<= 1) {
        int u = (t >= d) ? s[t - d] : 0;
        __syncthreads(); s[t] += u; __syncthreads();
    }
    if (t < NB) bsum[t] = s[t] - v;
}

__global__ void k_scan3(int* __restrict__ offs, const int* __restrict__ bsum) {
    int i = blockIdx.x * 256 + threadIdx.x;
    if (i < NN) offs[i] += bsum[i >> 8];
    if (i == NN) offs[NN] = EE;
}

__global__ void k_scatter(const int* __restrict__ ei, const int* __restrict__ offs,
                          int* __restrict__ curp, int2* __restrict__ sorted) {
    int i = blockIdx.x * 256 + threadIdx.x;
    if (i >= EE) return;
    int d = ei[EE + i];                       // dst row
    int pos = offs[d] + atomicAdd(&curp[d], 1);
    sorted[pos] = make_int2(ei[i], i);        // (src, edge id)
}

// ---------------------------------------------------------------------------
// K3: one wave per destination node. lane l owns channel l of head0 & head1
// (half2 interleave). out = (sum_e a*(v+e))/(sum_e a + eps) + skip
// ---------------------------------------------------------------------------
__global__ __launch_bounds__(256) void k_edge(
    const __half2* __restrict__ qt, const __half2* __restrict__ kt,
    const __half2* __restrict__ vt, const __half2* __restrict__ et,
    const int2* __restrict__ sorted, const int* __restrict__ offs,
    const float* __restrict__ skip, float* __restrict__ out)
{
    const int node = blockIdx.x * 4 + (threadIdx.x >> 6);
    const int lane = threadIdx.x & 63;
    if (node >= NN) return;
    const float K2E = 1.4426950408889634f / 8.0f;   // log2(e)/sqrt(OUT)

    float2 qf = __half22float2(qt[node * 64 + lane]);
    float s0 = 0.f, s1 = 0.f, a0 = 0.f, a1 = 0.f;
    const int beg = offs[node], end = offs[node + 1];

    for (int base = beg; base < end; base += 64) {
        int cnt = min(64, end - base);
        int2 myp = (lane < cnt) ? sorted[base + lane] : make_int2(0, 0);
        for (int i = 0; i < cnt; i++) {
            int src = __shfl(myp.x, i);
            int eid = __shfl(myp.y, i);
            float2 kf = __half22float2(kt[src * 64 + lane]);
            float2 vf = __half22float2(vt[src * 64 + lane]);
            float2 ef = __half22float2(et[(size_t)eid * 64 + lane]);
            float p0 = qf.x * (kf.x + ef.x);
            float p1 = qf.y * (kf.y + ef.y);
            #pragma unroll
            for (int m = 32; m; m >>= 1) {
                p0 += __shfl_xor(p0, m);
                p1 += __shfl_xor(p1, m);
            }
            float al0 = exp2f(p0 * K2E);
            float al1 = exp2f(p1 * K2E);
            s0 += al0; s1 += al1;
            a0 += al0 * (vf.x + ef.x);
            a1 += al1 * (vf.y + ef.y);
        }
    }
    float o0 = a0 / (s0 + 1e-16f) + skip[node * 128 + lane];
    float o1 = a1 / (s1 + 1e-16f) + skip[node * 128 + 64 + lane];
    out[node * 128 + lane] = o0;
    out[node * 128 + 64 + lane] = o1;
}

// ---------------------------------------------------------------------------
extern "C" void kernel_launch(void* const* d_in, const int* in_sizes, int n_in,
                              void* d_out, int out_size, void* d_ws, size_t ws_size,
                              hipStream_t stream) {
    const float* x   = (const float*)d_in[0];
    const int*   ei  = (const int*)d_in[1];     // [2][E]: row0 src, row1 dst
    const float* ea  = (const float*)d_in[2];
    const float* Wq  = (const float*)d_in[3];
    const float* bq  = (const float*)d_in[4];
    const float* Wk  = (const float*)d_in[5];
    const float* bk  = (const float*)d_in[6];
    const float* Wv  = (const float*)d_in[7];
    const float* bv  = (const float*)d_in[8];
    const float* We  = (const float*)d_in[9];
    const float* Wsk = (const float*)d_in[10];
    const float* bsk = (const float*)d_in[11];
    float* out = (float*)d_out;

    char* w = (char*)d_ws;
    __half* qt   = (__half*)(w + 0);                  // 12.8 MB
    __half* kt   = (__half*)(w + 12800000);           // 12.8 MB
    __half* vt   = (__half*)(w + 25600000);           // 12.8 MB
    float*  skip = (float*)(w + 38400000);            // 25.6 MB
    __half* et   = (__half*)(w + 64000000);           // 409.6 MB
    int2*   sorted = (int2*)(w + 473600000);          // 12.8 MB
    int*    cnt  = (int*)(w + 486400000);             // 200 KB (zeroed)
    int*    curp = (int*)(w + 486600000);             // 200 KB (zeroed)
    int*    bsum = (int*)(w + 486800000);             // 1 KB   (zeroed)
    int*    offs = (int*)(w + 486801024);             // 200 KB

    (void)hipMemsetAsync(w + 486400000, 0, 401024, stream);

    node_gemm<<<dim3(782, 4), 256, 0, stream>>>(x, Wq, bq, Wk, bk, Wv, bv, Wsk, bsk,
                                                qt, kt, vt, skip);
    edge_gemm<<<25000, 256, 0, stream>>>(ea, We, et);
    k_hist<<<6250, 256, 0, stream>>>(ei + EE, cnt);
    k_scan1<<<NB, 256, 0, stream>>>(cnt, offs, bsum);
    k_scan2<<<1, 256, 0, stream>>>(bsum);
    k_scan3<<<NB, 256, 0, stream>>>(offs, bsum);
    k_scatter<<<6250, 256, 0, stream>>>(ei, offs, curp, sorted);
    k_edge<<<12500, 256, 0, stream>>>((const __half2*)qt, (const __half2*)kt,
                                      (const __half2*)vt, (const __half2*)et,
                                      sorted, offs, skip, out);
}

// Round 3
// 1061.370 us; speedup vs baseline: 1.1003x; 1.1003x over previous
//
#include <hip/hip_runtime.h>
#include <hip/hip_fp16.h>

constexpr int NN = 50000;
constexpr int EE = 1600000;
constexpr int NB = 196;           // scan blocks: ceil(50000/256)

typedef __attribute__((ext_vector_type(8))) short bf16x8;
typedef __attribute__((ext_vector_type(4))) float f32x4;
typedef _Float16 half2v __attribute__((ext_vector_type(2)));

__device__ inline short f2bf(float f) {
    unsigned u = __builtin_bit_cast(unsigned, f);
    u += 0x7fff + ((u >> 16) & 1);      // RNE to bf16
    return (short)(u >> 16);
}

__device__ inline float fast_exp2(float x) {
#if __has_builtin(__builtin_amdgcn_exp2f)
    return __builtin_amdgcn_exp2f(x);
#else
    return exp2f(x);
#endif
}

__device__ inline float dot2(__half2 a, __half2 b) {
#if __has_builtin(__builtin_amdgcn_fdot2)
    return __builtin_amdgcn_fdot2(__builtin_bit_cast(half2v, a),
                                  __builtin_bit_cast(half2v, b), 0.f, false);
#else
    float2 af = __half22float2(a), bf = __half22float2(b);
    return af.x * bf.x + af.y * bf.y;
#endif
}

// ---------------------------------------------------------------------------
// K0: convert+transpose weights to bf16 once.
// Wtb[mat][n][k] (4*128*128), Wetb[n][k] (128*64)
// ---------------------------------------------------------------------------
__global__ void w_conv(const float* __restrict__ Wq, const float* __restrict__ Wk,
                       const float* __restrict__ Wv, const float* __restrict__ Ws,
                       const float* __restrict__ We,
                       short* __restrict__ Wtb, short* __restrict__ Wetb) {
    int i = blockIdx.x * 256 + threadIdx.x;
    if (i < 65536) {
        int mat = i >> 14, n = (i >> 7) & 127, k = i & 127;
        const float* W = mat == 0 ? Wq : mat == 1 ? Wk : mat == 2 ? Wv : Ws;
        Wtb[i] = f2bf(W[k * 128 + n]);
    } else {
        int j = i - 65536;                 // We: [k:64][n:128] -> [n][k]
        int n = j >> 6, k = j & 63;
        Wetb[j] = f2bf(We[k * 128 + n]);
    }
}

// ---------------------------------------------------------------------------
// K1: node GEMMs. blockIdx.y: 0=q, 1=k, 2=v, 3=skip.
// qt  : half2[node][hoff]  (hoff = h*32 + c2, channels (2c2,2c2+1) of head h)
// kvt : half2[node][2*hoff + {0=k,1=v}]
// skip: fp32 [node][128]
// ---------------------------------------------------------------------------
__global__ __launch_bounds__(256) void node_gemm(
    const float* __restrict__ x, const short* __restrict__ Wtb,
    const float* __restrict__ bq, const float* __restrict__ bk,
    const float* __restrict__ bv, const float* __restrict__ bs,
    __half2* __restrict__ qt, __half2* __restrict__ kvt,
    float* __restrict__ skip)
{
    __shared__ short As[64 * 128];    // [row][chunk^(row&15)][8]
    __shared__ short Bs[128 * 128];   // Wt: [n][chunk^(n&15)][8]
    const int tid = threadIdx.x;
    const int mat = blockIdx.y;
    const short* __restrict__ Wt = Wtb + mat * 16384;
    const float* __restrict__ bias = mat == 0 ? bq : mat == 1 ? bk : mat == 2 ? bv : bs;

    #pragma unroll
    for (int v8 = tid; v8 < 2048; v8 += 256) {       // Wt [n][k] bf16, 16B chunks
        int n = v8 >> 4, k8 = v8 & 15;
        int chunk = k8 ^ (n & 15);
        *(bf16x8*)&Bs[n * 128 + chunk * 8] = *(const bf16x8*)&Wt[n * 128 + k8 * 8];
    }
    const int row0 = blockIdx.x * 64;
    #pragma unroll
    for (int v4 = tid; v4 < 2048; v4 += 256) {       // x tile, float4 -> bf16x4
        int r = v4 >> 5, k4 = v4 & 31;
        int node = row0 + r;
        float4 xv = (node < NN) ? *(const float4*)&x[(size_t)node * 128 + k4 * 4]
                                : make_float4(0.f, 0.f, 0.f, 0.f);
        int k = k4 * 4;
        int chunk = (k >> 3) ^ (r & 15);
        *(short4*)&As[r * 128 + chunk * 8 + (k & 7)] =
            make_short4(f2bf(xv.x), f2bf(xv.y), f2bf(xv.z), f2bf(xv.w));
    }
    __syncthreads();

    const int wave = tid >> 6, lane = tid & 63;
    const int m16 = lane & 15, quad = lane >> 4;
    const int arow = wave * 16 + m16;
    f32x4 acc[8] = {};
    #pragma unroll
    for (int ks = 0; ks < 4; ks++) {
        int c = ks * 4 + quad;
        bf16x8 af = *(const bf16x8*)&As[arow * 128 + (c ^ (arow & 15)) * 8];
        #pragma unroll
        for (int t = 0; t < 8; t++) {
            int n = t * 16 + m16;
            bf16x8 bf = *(const bf16x8*)&Bs[n * 128 + (c ^ (n & 15)) * 8];
            acc[t] = __builtin_amdgcn_mfma_f32_16x16x32_bf16(af, bf, acc[t], 0, 0, 0);
        }
    }
    #pragma unroll
    for (int t = 0; t < 8; t++) {
        int col = t * 16 + m16;
        float bv_ = bias[col];
        int h = t >> 2;
        int c2 = (t & 3) * 8 + (m16 >> 1);
        int hoff = h * 32 + c2;
        #pragma unroll
        for (int r = 0; r < 4; r++) {
            int node = row0 + wave * 16 + quad * 4 + r;
            float val = acc[t][r] + bv_;
            float nb = __shfl_xor(val, 1);           // neighbor added its own bias
            if (node < NN) {
                if (mat == 3) {
                    skip[node * 128 + col] = val;
                } else if (!(m16 & 1)) {
                    __half2 hv = __halves2half2(__float2half(val), __float2half(nb));
                    if (mat == 0)      qt[node * 64 + hoff] = hv;
                    else if (mat == 1) kvt[node * 128 + 2 * hoff] = hv;
                    else               kvt[node * 128 + 2 * hoff + 1] = hv;
                }
            }
        }
    }
}

// ---------------------------------------------------------------------------
// K2: e = edge_attr[E,64] @ We[64,128] -> half2 et[edge][hoff]
// ---------------------------------------------------------------------------
__global__ __launch_bounds__(256) void edge_gemm(
    const float* __restrict__ ea, const short* __restrict__ Wetb,
    __half2* __restrict__ et)
{
    __shared__ short As[64 * 64];     // [row][chunk^(row&7)][8]
    __shared__ short Bs[128 * 64];    // Wet: [n][chunk^(n&7)][8]
    const int tid = threadIdx.x;
    #pragma unroll
    for (int v8 = tid; v8 < 1024; v8 += 256) {
        int n = v8 >> 3, k8 = v8 & 7;
        int chunk = k8 ^ (n & 7);
        *(bf16x8*)&Bs[n * 64 + chunk * 8] = *(const bf16x8*)&Wetb[n * 64 + k8 * 8];
    }
    const int row0 = blockIdx.x * 64;
    #pragma unroll
    for (int v4 = tid; v4 < 1024; v4 += 256) {
        int r = v4 >> 4, k4 = v4 & 15;
        float4 xv = *(const float4*)&ea[(size_t)(row0 + r) * 64 + k4 * 4];
        int k = k4 * 4;
        int chunk = (k >> 3) ^ (r & 7);
        *(short4*)&As[r * 64 + chunk * 8 + (k & 7)] =
            make_short4(f2bf(xv.x), f2bf(xv.y), f2bf(xv.z), f2bf(xv.w));
    }
    __syncthreads();

    const int wave = tid >> 6, lane = tid & 63;
    const int m16 = lane & 15, quad = lane >> 4;
    const int arow = wave * 16 + m16;
    f32x4 acc[8] = {};
    #pragma unroll
    for (int ks = 0; ks < 2; ks++) {
        int c = ks * 4 + quad;
        bf16x8 af = *(const bf16x8*)&As[arow * 64 + (c ^ (arow & 7)) * 8];
        #pragma unroll
        for (int t = 0; t < 8; t++) {
            int n = t * 16 + m16;
            bf16x8 bf = *(const bf16x8*)&Bs[n * 64 + (c ^ (n & 7)) * 8];
            acc[t] = __builtin_amdgcn_mfma_f32_16x16x32_bf16(af, bf, acc[t], 0, 0, 0);
        }
    }
    #pragma unroll
    for (int t = 0; t < 8; t++) {
        int h = t >> 2;
        int hoff = h * 32 + (t & 3) * 8 + (m16 >> 1);
        #pragma unroll
        for (int r = 0; r < 4; r++) {
            int edge = row0 + wave * 16 + quad * 4 + r;
            float a = acc[t][r];
            float b = __shfl_xor(a, 1);
            if (!(m16 & 1))
                et[(size_t)edge * 64 + hoff] =
                    __halves2half2(__float2half(a), __float2half(b));
        }
    }
}

// ---------------------------------------------------------------------------
// Counting sort of edges by dst: hist -> scan(3 kernels) -> scatter
// ---------------------------------------------------------------------------
__global__ void k_hist(const int* __restrict__ dst, int* __restrict__ cnt) {
    int i = blockIdx.x * 256 + threadIdx.x;
    if (i < EE) atomicAdd(&cnt[dst[i]], 1);
}

__global__ __launch_bounds__(256) void k_scan1(const int* __restrict__ cnt,
                                               int* __restrict__ offs,
                                               int* __restrict__ bsum) {
    __shared__ int s[256];
    int t = threadIdx.x, i = blockIdx.x * 256 + t;
    int v = (i < NN) ? cnt[i] : 0;
    s[t] = v; __syncthreads();
    #pragma unroll
    for (int d = 1; d < 256; d <<= 1) {
        int u = (t >= d) ? s[t - d] : 0;
        __syncthreads(); s[t] += u; __syncthreads();
    }
    if (i < NN) offs[i] = s[t] - v;
    if (t == 255) bsum[blockIdx.x] = s[255];
}

__global__ __launch_bounds__(256) void k_scan2(int* __restrict__ bsum) {
    __shared__ int s[256];
    int t = threadIdx.x;
    int v = (t < NB) ? bsum[t] : 0;
    s[t] = v; __syncthreads();
    #pragma unroll
    for (int d = 1; d < 256; d <<= 1) {
        int u = (t >= d) ? s[t - d] : 0;
        __syncthreads(); s[t] += u; __syncthreads();
    }
    if (t < NB) bsum[t] = s[t] - v;
}

__global__ void k_scan3(int* __restrict__ offs, const int* __restrict__ bsum) {
    int i = blockIdx.x * 256 + threadIdx.x;
    if (i < NN) offs[i] += bsum[i >> 8];
    if (i == NN) offs[NN] = EE;
}

__global__ void k_scatter(const int* __restrict__ ei, const int* __restrict__ offs,
                          int* __restrict__ curp, int2* __restrict__ sorted) {
    int i = blockIdx.x * 256 + threadIdx.x;
    if (i >= EE) return;
    int d = ei[EE + i];                       // dst row
    int pos = offs[d] + atomicAdd(&curp[d], 1);
    sorted[pos] = make_int2(ei[i], i);        // (src, edge id)
}

// ---------------------------------------------------------------------------
// K3: one wave per destination node. lane l = head (l>>5), channel pair (l&31).
// out = (sum_e a*(v+e))/(sum_e a + eps) + skip
// ---------------------------------------------------------------------------
__global__ __launch_bounds__(256) void k_edge(
    const __half2* __restrict__ qt, const uint2* __restrict__ kvt,
    const __half2* __restrict__ et,
    const int2* __restrict__ sorted, const int* __restrict__ offs,
    const float2* __restrict__ skip, float2* __restrict__ out)
{
    const int node = blockIdx.x * 4 + (threadIdx.x >> 6);
    const int lane = threadIdx.x & 63;
    if (node >= NN) return;
    const float K2E = 1.4426950408889634f / 8.0f;   // log2(e)/sqrt(OUT)
    const int hoff = (lane >> 5) * 32 + (lane & 31);

    __half2 qh = qt[node * 64 + hoff];
    float s = 0.f;
    float2 a = make_float2(0.f, 0.f);
    const int beg = offs[node], end = offs[node + 1];

    for (int base = beg; base < end; base += 64) {
        int cnt = min(64, end - base);
        int2 myp = (lane < cnt) ? sorted[base + lane] : make_int2(0, 0);
        int cnt4 = (cnt + 3) & ~3;
        for (int i0 = 0; i0 < cnt4; i0 += 4) {
            #pragma unroll
            for (int j = 0; j < 4; j++) {
                int i = i0 + j;
                int src = __shfl(myp.x, i);
                int eid = __shfl(myp.y, i);
                uint2 kv = kvt[src * 64 + hoff];
                __half2 kh = __builtin_bit_cast(__half2, kv.x);
                __half2 vh = __builtin_bit_cast(__half2, kv.y);
                __half2 eh = et[(size_t)eid * 64 + hoff];
                float p = dot2(qh, __hadd2(kh, eh));
                #pragma unroll
                for (int m = 1; m < 32; m <<= 1) p += __shfl_xor(p, m);
                float al = fast_exp2(p * K2E);
                al = (i < cnt) ? al : 0.f;
                s += al;
                float2 vef = __half22float2(__hadd2(vh, eh));
                a.x = fmaf(al, vef.x, a.x);
                a.y = fmaf(al, vef.y, a.y);
            }
        }
    }
    float inv = 1.f / (s + 1e-16f);
    float2 sk = skip[node * 64 + hoff];
    out[node * 64 + hoff] = make_float2(a.x * inv + sk.x, a.y * inv + sk.y);
}

// ---------------------------------------------------------------------------
extern "C" void kernel_launch(void* const* d_in, const int* in_sizes, int n_in,
                              void* d_out, int out_size, void* d_ws, size_t ws_size,
                              hipStream_t stream) {
    const float* x   = (const float*)d_in[0];
    const int*   ei  = (const int*)d_in[1];     // [2][E]: row0 src, row1 dst
    const float* ea  = (const float*)d_in[2];
    const float* Wq  = (const float*)d_in[3];
    const float* bq  = (const float*)d_in[4];
    const float* Wk  = (const float*)d_in[5];
    const float* bk  = (const float*)d_in[6];
    const float* Wv  = (const float*)d_in[7];
    const float* bv  = (const float*)d_in[8];
    const float* We  = (const float*)d_in[9];
    const float* Wsk = (const float*)d_in[10];
    const float* bsk = (const float*)d_in[11];
    float* out = (float*)d_out;

    char* w = (char*)d_ws;
    __half2* qt  = (__half2*)(w + 0);                 // 12.8 MB
    __half2* kvt = (__half2*)(w + 12800000);          // 25.6 MB interleaved k/v
    float*  skip = (float*)(w + 38400000);            // 25.6 MB
    __half2* et  = (__half2*)(w + 64000000);          // 409.6 MB
    int2*   sorted = (int2*)(w + 473600000);          // 12.8 MB
    int*    cnt  = (int*)(w + 486400000);             // 200 KB (zeroed)
    int*    curp = (int*)(w + 486600000);             // 200 KB (zeroed)
    int*    bsum = (int*)(w + 486800000);             // 1 KB   (zeroed)
    int*    offs = (int*)(w + 486801024);             // 200 KB
    short*  Wtb  = (short*)(w + 487100000);           // 128 KB bf16 W^T x4
    short*  Wetb = (short*)(w + 487231072);           // 16 KB bf16 We^T

    (void)hipMemsetAsync(w + 486400000, 0, 401024, stream);

    w_conv<<<288, 256, 0, stream>>>(Wq, Wk, Wv, Wsk, We, Wtb, Wetb);
    node_gemm<<<dim3(782, 4), 256, 0, stream>>>(x, Wtb, bq, bk, bv, bsk,
                                                qt, (__half2*)kvt, skip);
    edge_gemm<<<25000, 256, 0, stream>>>(ea, Wetb, et);
    k_hist<<<6250, 256, 0, stream>>>(ei + EE, cnt);
    k_scan1<<<NB, 256, 0, stream>>>(cnt, offs, bsum);
    k_scan2<<<1, 256, 0, stream>>>(bsum);
    k_scan3<<<NB, 256, 0, stream>>>(offs, bsum);
    k_scatter<<<6250, 256, 0, stream>>>(ei, offs, curp, sorted);
    k_edge<<<12500, 256, 0, stream>>>(qt, (const uint2*)kvt, et,
                                      sorted, offs, (const float2*)skip,
                                      (float2*)out);
}